// Round 1
// baseline (252.715 us; speedup 1.0000x reference)
//
#include <hip/hip_runtime.h>

typedef __bf16 bf16x8 __attribute__((ext_vector_type(8)));
typedef float f32x4 __attribute__((ext_vector_type(4)));
typedef unsigned short u16;
typedef u16 u16x8 __attribute__((ext_vector_type(8)));
typedef u16 u16x4 __attribute__((ext_vector_type(4)));

__device__ __forceinline__ u16 f2bf(float f) {
    unsigned int u = __builtin_bit_cast(unsigned int, f);
    u += 0x7fffu + ((u >> 16) & 1u);   // RNE
    return (u16)(u >> 16);
}

__device__ __forceinline__ f32x4 mfma16(u16x8 a, u16x8 b, f32x4 c) {
    return __builtin_amdgcn_mfma_f32_16x16x32_bf16(
        __builtin_bit_cast(bf16x8, a), __builtin_bit_cast(bf16x8, b), c, 0, 0, 0);
}

// ---------------------------------------------------------------------------
// Kernel 1: QKV projection. x[16384,512] fp32 @ W[512,128] fp32 -> bf16 out.
// q is pre-scaled by 1/sqrt(128).
// Block: 256 thr (4 waves), tile 128(M) x 128(N), BK=64, K=512.
// ---------------------------------------------------------------------------
__global__ __launch_bounds__(256) void qkv_proj(
    const float* __restrict__ x, const float* __restrict__ Wq,
    const float* __restrict__ Wk, const float* __restrict__ Wv,
    u16* __restrict__ qb, u16* __restrict__ kb, u16* __restrict__ vb)
{
    const int DIN = 512, DOUT = 128;
    __shared__ u16 xs[128][72];   // x tile, rows padded to 72 (2-way banks)
    __shared__ u16 wt[128][72];   // W tile TRANSPOSED: wt[n][k]

    const int tid  = threadIdx.x;
    const int lane = tid & 63, wid = tid >> 6;
    const int g = lane >> 4, l16 = lane & 15;
    const int row0 = blockIdx.x * 128;
    const int widx = blockIdx.y;
    const float* W = (widx == 0) ? Wq : (widx == 1 ? Wk : Wv);
    u16* out = (widx == 0) ? qb : (widx == 1 ? kb : vb);

    const f32x4 fzero = {0.f, 0.f, 0.f, 0.f};
    f32x4 acc[2][8];
    for (int t = 0; t < 2; ++t)
        for (int n = 0; n < 8; ++n) acc[t][n] = fzero;

    for (int k0 = 0; k0 < DIN; k0 += 64) {
        // stage x tile (coalesced float4), convert to bf16
        for (int it = 0; it < 8; ++it) {
            int r = (tid >> 4) + it * 16;
            int c = (tid & 15) * 4;
            float4 v = *(const float4*)(x + (size_t)(row0 + r) * DIN + k0 + c);
            xs[r][c + 0] = f2bf(v.x); xs[r][c + 1] = f2bf(v.y);
            xs[r][c + 2] = f2bf(v.z); xs[r][c + 3] = f2bf(v.w);
        }
        // stage W tile transposed
        for (int it = 0; it < 8; ++it) {
            int kr = (tid >> 5) + it * 8;
            int c  = (tid & 31) * 4;
            float4 v = *(const float4*)(W + (size_t)(k0 + kr) * DOUT + c);
            wt[c + 0][kr] = f2bf(v.x); wt[c + 1][kr] = f2bf(v.y);
            wt[c + 2][kr] = f2bf(v.z); wt[c + 3][kr] = f2bf(v.w);
        }
        __syncthreads();

        for (int ks = 0; ks < 64; ks += 32) {
            u16x8 a[2], b[8];
            for (int t = 0; t < 2; ++t)
                a[t] = *(const u16x8*)&xs[wid * 32 + t * 16 + l16][ks + 8 * g];
            for (int n = 0; n < 8; ++n)
                b[n] = *(const u16x8*)&wt[n * 16 + l16][ks + 8 * g];
            for (int t = 0; t < 2; ++t)
                for (int n = 0; n < 8; ++n)
                    acc[t][n] = mfma16(a[t], b[n], acc[t][n]);
        }
        __syncthreads();
    }

    const float scale = (widx == 0) ? 0.08838834764831845f : 1.0f; // 1/sqrt(128)
    for (int t = 0; t < 2; ++t)
        for (int n = 0; n < 8; ++n)
            for (int r = 0; r < 4; ++r) {
                int row = row0 + wid * 32 + t * 16 + g * 4 + r; // C/D: row=(lane>>4)*4+reg
                int col = n * 16 + l16;                         // C/D: col=lane&15
                out[(size_t)row * DOUT + col] = f2bf(acc[t][n][r] * scale);
            }
}

// ---------------------------------------------------------------------------
// Kernel 2: causal flash attention. Q-tile 64 (wave owns 16 rows), K-tile 64.
// Swapped QK^T: S^T = mfma(K, Q^T)  -> lane owns one q row (col=lane&15).
// PV swapped:  O^T = mfma(V^T, P^T) -> V transposed into LDS at staging.
// ---------------------------------------------------------------------------
__global__ __launch_bounds__(256) void attn(
    const u16* __restrict__ qb, const u16* __restrict__ kb,
    const u16* __restrict__ vb, float* __restrict__ out)
{
    const int S = 4096, D = 128, NB = 4;
    __shared__ u16 Klds[64 * 128];       // XOR-swizzled rows, 16 KB
    __shared__ u16 Vt[128][72];          // V transposed [e][k], 18 KB
    __shared__ u16 Plds[4][16][72];      // per-wave P [q][k], 9 KB

    const int tid = threadIdx.x, lane = tid & 63, wid = tid >> 6;
    const int g = lane >> 4, l16 = lane & 15;
    const int nq = S / 64;
    const int t = nq - 1 - (blockIdx.x / NB);   // longest-job-first
    const int batch = blockIdx.x % NB;
    const int q0 = t * 64;
    const int qrow0 = q0 + wid * 16;

    const u16* qB = qb + (size_t)batch * S * D;
    const u16* kB = kb + (size_t)batch * S * D;
    const u16* vB = vb + (size_t)batch * S * D;

    // Q fragments held in registers for the whole block (pre-scaled by 1/sqrt(D))
    u16x8 qf[4];
    for (int ds = 0; ds < 4; ++ds)
        qf[ds] = *(const u16x8*)&qB[(size_t)(qrow0 + l16) * D + ds * 32 + 8 * g];

    const f32x4 fzero = {0.f, 0.f, 0.f, 0.f};
    f32x4 o[8];
    for (int e = 0; e < 8; ++e) o[e] = fzero;
    float m = -1e30f, l = 0.0f;

    for (int k0 = 0; k0 <= q0; k0 += 64) {
        // ---- stage K (swizzled) + V (transposed) ----
        for (int it = 0; it < 4; ++it) {
            int c = tid + it * 256;           // 1024 chunks of 16B
            int row = c >> 4, col16 = c & 15;
            u16x8 kv = *(const u16x8*)&kB[(size_t)(k0 + row) * D + col16 * 8];
            int byteInRow = (col16 * 16) ^ ((row & 7) << 4);
            *(u16x8*)&Klds[row * 128 + (byteInRow >> 1)] = kv;
            u16x8 vv = *(const u16x8*)&vB[(size_t)(k0 + row) * D + col16 * 8];
            for (int j = 0; j < 8; ++j) Vt[col16 * 8 + j][row] = vv[j];
        }
        __syncthreads();

        // ---- S^T = K * Q^T ----
        f32x4 st[4];
        for (int kt = 0; kt < 4; ++kt) {
            st[kt] = fzero;
            for (int ds = 0; ds < 4; ++ds) {
                int row = kt * 16 + l16;
                int byteInRow = (ds * 64 + 16 * g) ^ ((row & 7) << 4);
                u16x8 kf = *(const u16x8*)&Klds[row * 128 + (byteInRow >> 1)];
                st[kt] = mfma16(kf, qf[ds], st[kt]);
            }
        }

        // ---- causal mask (only the diagonal tile needs it) ----
        const int qg = qrow0 + l16;
        if (k0 + 63 > qrow0) {
            for (int kt = 0; kt < 4; ++kt)
                for (int r = 0; r < 4; ++r) {
                    int kg = k0 + kt * 16 + g * 4 + r;  // C/D row = k index
                    if (kg > qg) st[kt][r] = -1e30f;
                }
        }

        // ---- online softmax (lane owns row q=qg; partners at lane^16, lane^32) ----
        float pm = -1e30f;
        for (int kt = 0; kt < 4; ++kt)
            for (int r = 0; r < 4; ++r) pm = fmaxf(pm, st[kt][r]);
        pm = fmaxf(pm, __shfl_xor(pm, 16));
        pm = fmaxf(pm, __shfl_xor(pm, 32));
        float mnew = fmaxf(m, pm);
        float alpha = __expf(m - mnew);
        float lsum = 0.f;
        for (int kt = 0; kt < 4; ++kt) {
            u16x4 pk;
            for (int r = 0; r < 4; ++r) {
                float p = __expf(st[kt][r] - mnew);
                lsum += p;
                pk[r] = f2bf(p);
            }
            *(u16x4*)&Plds[wid][l16][kt * 16 + g * 4] = pk;  // P[q][k] bf16
        }
        lsum += __shfl_xor(lsum, 16);
        lsum += __shfl_xor(lsum, 32);
        l = l * alpha + lsum;
        m = mnew;
        for (int e = 0; e < 8; ++e)
            for (int r = 0; r < 4; ++r) o[e][r] *= alpha;

        // ---- O^T += V^T * P^T ----
        for (int ks = 0; ks < 2; ++ks) {
            u16x8 pf = *(const u16x8*)&Plds[wid][l16][ks * 32 + 8 * g];
            for (int e = 0; e < 8; ++e) {
                u16x8 vf = *(const u16x8*)&Vt[e * 16 + l16][ks * 32 + 8 * g];
                o[e] = mfma16(vf, pf, o[e]);
            }
        }
        __syncthreads();
    }

    // ---- epilogue: O^T[e][q] / l -> out[batch][q][e] (fp32) ----
    const int qg = qrow0 + l16;
    const float inv = 1.0f / l;
    float* outp = out + ((size_t)batch * S + qg) * D;
    for (int e = 0; e < 8; ++e)
        for (int r = 0; r < 4; ++r)
            outp[e * 16 + g * 4 + r] = o[e][r] * inv;
}

extern "C" void kernel_launch(void* const* d_in, const int* in_sizes, int n_in,
                              void* d_out, int out_size, void* d_ws, size_t ws_size,
                              hipStream_t stream) {
    (void)in_sizes; (void)n_in; (void)out_size; (void)ws_size;
    const int B = 4, S = 4096, DOUT = 128;
    const float* x  = (const float*)d_in[0];
    const float* Wq = (const float*)d_in[1];
    const float* Wk = (const float*)d_in[2];
    const float* Wv = (const float*)d_in[3];
    float* out = (float*)d_out;

    u16* qbuf = (u16*)d_ws;                       // 3 x [B*S, 128] bf16 = 12.6 MB
    u16* kbuf = qbuf + (size_t)B * S * DOUT;
    u16* vbuf = kbuf + (size_t)B * S * DOUT;

    qkv_proj<<<dim3(B * S / 128, 3), 256, 0, stream>>>(x, Wq, Wk, Wv, qbuf, kbuf, vbuf);
    attn<<<dim3(B * S / 64), 256, 0, stream>>>(qbuf, kbuf, vbuf, out);
}

// Round 2
// 226.554 us; speedup vs baseline: 1.1155x; 1.1155x over previous
//
#include <hip/hip_runtime.h>

typedef __bf16 bf16x8 __attribute__((ext_vector_type(8)));
typedef float f32x4 __attribute__((ext_vector_type(4)));
typedef unsigned short u16;
typedef unsigned int u32;
typedef u16 u16x8 __attribute__((ext_vector_type(8)));
typedef u16 u16x4 __attribute__((ext_vector_type(4)));
typedef u32 u32x4 __attribute__((ext_vector_type(4)));

__device__ __forceinline__ u16 f2bf(float f) {
    u32 u = __builtin_bit_cast(u32, f);
    u += 0x7fffu + ((u >> 16) & 1u);   // RNE
    return (u16)(u >> 16);
}
__device__ __forceinline__ u32 pack2(float a, float b) {
    return (u32)f2bf(a) | ((u32)f2bf(b) << 16);
}
__device__ __forceinline__ f32x4 mfma16(u16x8 a, u16x8 b, f32x4 c) {
    return __builtin_amdgcn_mfma_f32_16x16x32_bf16(
        __builtin_bit_cast(bf16x8, a), __builtin_bit_cast(bf16x8, b), c, 0, 0, 0);
}

// ---------------------------------------------------------------------------
// Kernel 0: transpose W fp32 [512][128] -> Wt bf16 [3][128][512]
// ---------------------------------------------------------------------------
__global__ __launch_bounds__(256) void transpose_w(
    const float* __restrict__ Wq, const float* __restrict__ Wk,
    const float* __restrict__ Wv, u16* __restrict__ wt)
{
    int w = blockIdx.x >> 5;                          // 32 blocks per matrix
    int local = ((blockIdx.x & 31) << 8) + threadIdx.x;  // [0, 8192)
    int n = local & 127;
    int k0 = (local >> 7) << 3;
    const float* W = (w == 0) ? Wq : (w == 1 ? Wk : Wv);
    u16x8 v;
    #pragma unroll
    for (int i = 0; i < 8; ++i) v[i] = f2bf(W[(size_t)(k0 + i) * 128 + n]);
    *(u16x8*)&wt[((size_t)w * 128 + n) * 512 + k0] = v;
}

// ---------------------------------------------------------------------------
// Kernel 1: QKV projection, LDS-free. Wave owns 16 rows x 128 cols, K=512.
// q pre-scaled by 1/sqrt(128); v written TRANSPOSED [B][128][S].
// ---------------------------------------------------------------------------
__global__ __launch_bounds__(256) void qkv_proj(
    const float* __restrict__ x, const u16* __restrict__ wt,
    u16* __restrict__ qb, u16* __restrict__ kb, u16* __restrict__ vt)
{
    const int DIN = 512, D = 128;
    const int tid = threadIdx.x, lane = tid & 63, wid = tid >> 6;
    const int g = lane >> 4, l16 = lane & 15;
    const int widx = blockIdx.y;
    const int r0 = blockIdx.x * 64 + wid * 16;
    const u16* W = wt + (size_t)widx * 128 * 512;

    const f32x4 fz = {0.f, 0.f, 0.f, 0.f};
    f32x4 acc[8];
    #pragma unroll
    for (int n = 0; n < 8; ++n) acc[n] = fz;

    const float* xr = x + (size_t)(r0 + l16) * DIN + 8 * g;
    #pragma unroll 4
    for (int k0 = 0; k0 < DIN; k0 += 32) {
        float4 xa = *(const float4*)(xr + k0);
        float4 xb = *(const float4*)(xr + k0 + 4);
        u32x4 ad = { pack2(xa.x, xa.y), pack2(xa.z, xa.w),
                     pack2(xb.x, xb.y), pack2(xb.z, xb.w) };
        u16x8 a = __builtin_bit_cast(u16x8, ad);
        #pragma unroll
        for (int n = 0; n < 8; ++n) {
            u16x8 b = *(const u16x8*)&W[(size_t)(n * 16 + l16) * 512 + k0 + 8 * g];
            acc[n] = mfma16(a, b, acc[n]);
        }
    }

    if (widx < 2) {
        const float scale = (widx == 0) ? 0.08838834764831845f : 1.0f;
        u16* out = (widx == 0) ? qb : kb;
        #pragma unroll
        for (int n = 0; n < 8; ++n) {
            u16x4 pv;
            #pragma unroll
            for (int r = 0; r < 4; ++r) pv[r] = f2bf(acc[n][r] * scale);
            // C/D: row = 4g+r (rel), col = n*16+l16 -> scatter 4 rows, scalar u16
            #pragma unroll
            for (int r = 0; r < 4; ++r)
                out[(size_t)(r0 + g * 4 + r) * D + n * 16 + l16] = pv[r];
        }
    } else {
        const int b = r0 >> 12, s = r0 & 4095;
        #pragma unroll
        for (int n = 0; n < 8; ++n) {
            u16x4 pv;
            #pragma unroll
            for (int r = 0; r < 4; ++r) pv[r] = f2bf(acc[n][r]);
            *(u16x4*)&vt[((size_t)b * 128 + n * 16 + l16) * 4096 + s + g * 4] = pv;
        }
    }
}

// ---------------------------------------------------------------------------
// Kernel 2: causal flash attention, 1 wave = 16 q-rows, split-K chunks.
// No LDS, no barriers. K/V^T fragments loaded global->reg (L2-resident).
// ---------------------------------------------------------------------------
__global__ __launch_bounds__(256) void attn2(
    const u16* __restrict__ qb, const u16* __restrict__ kb,
    const u16* __restrict__ vt, float* __restrict__ out,
    float* __restrict__ po, float* __restrict__ pml,
    int cmax, int chunk)
{
    const int S = 4096, D = 128;
    const int tid = threadIdx.x, lane = tid & 63, wid = tid >> 6;
    const int g = lane >> 4, l16 = lane & 15;
    const int wgid = blockIdx.x * 4 + wid;
    const int per_qt = 4 * cmax;
    const int qt = 255 - wgid / per_qt;
    const int rem = wgid % per_qt;
    const int b = rem / cmax, c = rem % cmax;
    const int q0 = qt * 16;
    const int klen = q0 + 16;
    const int nch = (klen + chunk - 1) / chunk;
    if (c >= nch) return;
    const int k_lo = c * chunk;
    const int k_hi = min(k_lo + chunk, klen);

    const u16* qB = qb + (size_t)b * S * D;
    const u16* kB = kb + (size_t)b * S * D;
    const u16* vB = vt + (size_t)b * D * S;   // [e][s]

    u16x8 qf[4];
    #pragma unroll
    for (int ds = 0; ds < 4; ++ds)
        qf[ds] = *(const u16x8*)&qB[(size_t)(q0 + l16) * D + ds * 32 + 8 * g];

    const f32x4 fz = {0.f, 0.f, 0.f, 0.f};
    f32x4 o[8];
    #pragma unroll
    for (int e = 0; e < 8; ++e) o[e] = fz;
    float m = -3e38f, l = 0.0f;

    const int srcA = l16 + ((g & 1) << 5);
    const int srcB = srcA + 16;
    const bool hiSel = (g >= 2);
    const int qg = q0 + l16;

    for (int k0 = k_lo; k0 < k_hi; k0 += 64) {
        // ---- S^T = K * Q^T ----
        f32x4 st[4];
        #pragma unroll
        for (int kt = 0; kt < 4; ++kt) {
            st[kt] = fz;
            #pragma unroll
            for (int ds = 0; ds < 4; ++ds) {
                u16x8 kf = *(const u16x8*)&kB[(size_t)(k0 + kt * 16 + l16) * D + ds * 32 + 8 * g];
                st[kt] = mfma16(kf, qf[ds], st[kt]);
            }
        }
        // ---- causal mask (diagonal tiles only) ----
        if (k0 + 63 > q0) {
            #pragma unroll
            for (int kt = 0; kt < 4; ++kt)
                #pragma unroll
                for (int r = 0; r < 4; ++r) {
                    int kg = k0 + kt * 16 + g * 4 + r;
                    if (kg > qg) st[kt][r] = -1e30f;
                }
        }
        // ---- online softmax (lane owns row qg; partners at lane^16, lane^32) ----
        float pm = -3e38f;
        #pragma unroll
        for (int kt = 0; kt < 4; ++kt)
            pm = fmaxf(pm, fmaxf(fmaxf(st[kt][0], st[kt][1]), fmaxf(st[kt][2], st[kt][3])));
        pm = fmaxf(pm, __shfl_xor(pm, 16));
        pm = fmaxf(pm, __shfl_xor(pm, 32));
        float mnew = fmaxf(m, pm);
        float alpha = __expf(m - mnew);
        float lsum = 0.f;
        u32 pkd[4][2];
        #pragma unroll
        for (int kt = 0; kt < 4; ++kt) {
            float p0 = __expf(st[kt][0] - mnew), p1 = __expf(st[kt][1] - mnew);
            float p2 = __expf(st[kt][2] - mnew), p3 = __expf(st[kt][3] - mnew);
            lsum += (p0 + p1) + (p2 + p3);
            pkd[kt][0] = pack2(p0, p1);
            pkd[kt][1] = pack2(p2, p3);
        }
        lsum += __shfl_xor(lsum, 16);
        lsum += __shfl_xor(lsum, 32);
        l = l * alpha + lsum;
        m = mnew;
        #pragma unroll
        for (int e = 0; e < 8; ++e)
            #pragma unroll
            for (int r = 0; r < 4; ++r) o[e][r] *= alpha;

        // ---- P redistribution in-register + O^T += V^T * P^T ----
        #pragma unroll
        for (int ksel = 0; ksel < 2; ++ksel) {
            u32 lo0 = __shfl((int)pkd[2 * ksel][0], srcA), hi0 = __shfl((int)pkd[2 * ksel + 1][0], srcA);
            u32 lo1 = __shfl((int)pkd[2 * ksel][1], srcA), hi1 = __shfl((int)pkd[2 * ksel + 1][1], srcA);
            u32 lo2 = __shfl((int)pkd[2 * ksel][0], srcB), hi2 = __shfl((int)pkd[2 * ksel + 1][0], srcB);
            u32 lo3 = __shfl((int)pkd[2 * ksel][1], srcB), hi3 = __shfl((int)pkd[2 * ksel + 1][1], srcB);
            u32x4 dw = { hiSel ? hi0 : lo0, hiSel ? hi1 : lo1,
                         hiSel ? hi2 : lo2, hiSel ? hi3 : lo3 };
            u16x8 pf = __builtin_bit_cast(u16x8, dw);
            #pragma unroll
            for (int e = 0; e < 8; ++e) {
                u16x8 vf = *(const u16x8*)&vB[(size_t)(e * 16 + l16) * S + k0 + ksel * 32 + 8 * g];
                o[e] = mfma16(vf, pf, o[e]);
            }
        }
    }

    if (nch == 1) {
        const float inv = 1.0f / l;
        float* op = out + ((size_t)b * S + qg) * D;
        #pragma unroll
        for (int e = 0; e < 8; ++e) {
            f32x4 v = o[e];
            v[0] *= inv; v[1] *= inv; v[2] *= inv; v[3] *= inv;
            *(f32x4*)&op[e * 16 + g * 4] = v;
        }
    } else {
        const int slot = ((b * 192 + (qt - 64)) << 2) + c;
        float* pp = po + ((size_t)slot * 16 + l16) * 128;
        #pragma unroll
        for (int e = 0; e < 8; ++e)
            *(f32x4*)&pp[e * 16 + g * 4] = o[e];
        if (g == 0) {
            *(float2*)&pml[slot * 32 + l16 * 2] = make_float2(m, l);
        }
    }
}

// ---------------------------------------------------------------------------
// Kernel 3: merge split-K partials for qt in [64,256). 1 thread = 2 cols.
// ---------------------------------------------------------------------------
__global__ __launch_bounds__(256) void merge_k(
    const float* __restrict__ po, const float* __restrict__ pml,
    float* __restrict__ out)
{
    int gid = blockIdx.x * 256 + threadIdx.x;
    int rowId = gid >> 6;
    int cp = (gid & 63) << 1;
    int b = rowId / 3072;
    int rem = rowId % 3072;
    int qtl = rem >> 4, qr = rem & 15;
    int qt = qtl + 64;
    int nch = qt / 64 + 1;
    int slot0 = (b * 192 + qtl) << 2;

    float mv[4], lv[4];
    float ms = -3e38f;
    #pragma unroll
    for (int c = 0; c < 4; ++c) {
        if (c < nch) {
            float2 mlv = *(const float2*)&pml[(slot0 + c) * 32 + qr * 2];
            mv[c] = mlv.x; lv[c] = mlv.y;
            ms = fmaxf(ms, mv[c]);
        }
    }
    float den = 0.f, n0 = 0.f, n1 = 0.f;
    #pragma unroll
    for (int c = 0; c < 4; ++c) {
        if (c < nch) {
            float w = __expf(mv[c] - ms);
            den += w * lv[c];
            const float* p = po + ((size_t)(slot0 + c) * 16 + qr) * 128 + cp;
            n0 += w * p[0];
            n1 += w * p[1];
        }
    }
    float inv = 1.0f / den;
    *(float2*)&out[((size_t)b * 4096 + qt * 16 + qr) * 128 + cp] =
        make_float2(n0 * inv, n1 * inv);
}

extern "C" void kernel_launch(void* const* d_in, const int* in_sizes, int n_in,
                              void* d_out, int out_size, void* d_ws, size_t ws_size,
                              hipStream_t stream) {
    (void)in_sizes; (void)n_in; (void)out_size;
    const int B = 4, S = 4096, D = 128;
    const float* x  = (const float*)d_in[0];
    const float* Wq = (const float*)d_in[1];
    const float* Wk = (const float*)d_in[2];
    const float* Wv = (const float*)d_in[3];
    float* out = (float*)d_out;

    u16* qb = (u16*)d_ws;
    u16* kb = qb + (size_t)B * S * D;
    u16* vt = kb + (size_t)B * S * D;
    u16* wt = vt + (size_t)B * S * D;
    size_t base = (size_t)B * S * D * 3 * 2 + (size_t)3 * 128 * 512 * 2; // 12,976,128 B
    const size_t po_bytes = (size_t)3072 * 16 * 128 * 4;                 // 25,165,824 B
    const size_t ml_bytes = (size_t)3072 * 16 * 2 * 4;                   //    393,216 B
    bool split = ws_size >= base + po_bytes + ml_bytes;
    float* po  = split ? (float*)((char*)d_ws + base) : (float*)d_ws;
    float* pml = split ? (float*)((char*)d_ws + base + po_bytes) : (float*)d_ws;

    transpose_w<<<96, 256, 0, stream>>>(Wq, Wk, Wv, wt);
    qkv_proj<<<dim3(B * S / 64, 3), 256, 0, stream>>>(x, wt, qb, kb, vt);
    if (split) {
        attn2<<<1024, 256, 0, stream>>>(qb, kb, vt, out, po, pml, 4, 1024);
        merge_k<<<3072, 256, 0, stream>>>(po, pml, out);
    } else {
        attn2<<<256, 256, 0, stream>>>(qb, kb, vt, out, po, pml, 1, 1 << 28);
    }
}